// Round 8
// baseline (124.827 us; speedup 1.0000x reference)
//
#include <hip/hip_runtime.h>
#include <hip/hip_fp16.h>

// y[e, o] = sum_i weight[widx[e]][o][i] * values[iidx[e]][i]
// E = 1e6, N_W = 1024, D_IN = D_OUT = 16, fp32 in/out.
//
// History: R1 naive 137us. R3-R10 sort+mv 146us total. R11 direct 81us.
// R13 4-wave 73us. R14 fp16 W 67us. R15 VMEM 132->54: 53us. R16 fp16 x +
// fdot2: 51.5us. R17 y-staged stores (VMEM 42) + idx 2-deep: 44-48us,
// conflicts 0, VGPR 36.
// Model (R13-R17 fit): cy/batch = 17.4*VMEM_instr + 0.46*lines + C, C~614.
// VMEM at fp16 floor (32 W + 4 x + 2 idx + 4 st, all full-width). C =
// W-latency residue: depth-2 W buffer covers only ~50cy of ~200cy L2
// latency; duty 0.25 x 3.7 waves/SIMD = 0.93 < 1 -> CU idles every group.
//
// R18: W pipeline depth 2 -> 4 (four named reg pairs, prologue issues 8KB
// of W, steady state COMP4(K); WPAIR(K+4)). Cover ~150cy -> duty 0.5 ->
// overlap 1.85 > 1. Cost +16 VGPR (~52-68, within cap, same occ step).
// Predicted: steady 44-48 -> 36-40us (total ~114-118), VGPR ~52-68,
// FETCH/WRITE/conflicts flat, absmax 0.125. If flat at VGPR~68: C is
// cross-pipe issue serialization -> structure is ~15% off its VMEM floor
// (~29us) and wave-specialization is past the complexity knee.

#define D 16
#define WPB 4            // waves per block
#define TPB (WPB * 64)
#define MAXBLK 2048

typedef _Float16 h2v __attribute__((ext_vector_type(2)));

// ---------------- fallback naive kernel (R1, 137us) ----------------
__global__ __launch_bounds__(256) void linear_gather_mv(
    const float* __restrict__ values, const float* __restrict__ weight,
    const int* __restrict__ input_idx, const int* __restrict__ weight_idx,
    float* __restrict__ out, int E)
{
    int tid = blockIdx.x * blockDim.x + threadIdx.x;
    int e = tid >> 2;
    int j = tid & 3;
    if (e >= E) return;
    int ii = input_idx[e];
    int wi = weight_idx[e];
    const float4* xp = (const float4*)(values + (long long)ii * D);
    float4 x0 = xp[0], x1 = xp[1], x2 = xp[2], x3 = xp[3];
    const float4* wp = (const float4*)(weight + (long long)wi * (D * D) + j * (4 * D));
    float4 acc;
    float* accp = (float*)&acc;
    #pragma unroll
    for (int r = 0; r < 4; ++r) {
        float4 w0 = wp[r * 4 + 0], w1 = wp[r * 4 + 1], w2 = wp[r * 4 + 2], w3 = wp[r * 4 + 3];
        accp[r] = w0.x * x0.x + w0.y * x0.y + w0.z * x0.z + w0.w * x0.w
                + w1.x * x1.x + w1.y * x1.y + w1.z * x1.z + w1.w * x1.w
                + w2.x * x2.x + w2.y * x2.y + w2.z * x2.z + w2.w * x2.w
                + w3.x * x3.x + w3.y * x3.y + w3.z * x3.z + w3.w * x3.w;
    }
    ((float4*)out)[(long long)e * 4 + j] = acc;
}

// ---------------- W fp32 -> fp16 conversion ----------------
__global__ __launch_bounds__(256) void wconv(
    const float* __restrict__ w, __half* __restrict__ wh, int n)
{
    int i = (blockIdx.x * 256 + threadIdx.x) * 4;
    if (i + 3 >= n) {
        for (int k = i; k < n; ++k) wh[k] = __float2half(w[k]);
        return;
    }
    float4 v = *(const float4*)(w + i);
    __half2 a = __floats2half2_rn(v.x, v.y);
    __half2 b = __floats2half2_rn(v.z, v.w);
    float2 packed;
    ((__half2*)&packed)[0] = a;
    ((__half2*)&packed)[1] = b;
    *(float2*)(wh + i) = packed;
}

// ---- W load: TWO fp16 matrices per dwordx4 instruction ----
// W0 covers conns 4K+{0,1} (lh selects), W1 covers 4K+{2,3}. lane's 16B =
// float4 #(lane&31) of the 512B matrix = row (lane&31)>>1, cols 8h..8h+7.
#define WPAIR(K, W0, W1) do {                                                  \
    int a0 = __builtin_amdgcn_readlane(wcur, 4*(K)+0);                         \
    int a1 = __builtin_amdgcn_readlane(wcur, 4*(K)+1);                         \
    int a2 = __builtin_amdgcn_readlane(wcur, 4*(K)+2);                         \
    int a3 = __builtin_amdgcn_readlane(wcur, 4*(K)+3);                         \
    W0 = ((const float4*)(wh + (long long)(lh ? a1 : a0) * (D*D)))[hrow];      \
    W1 = ((const float4*)(wh + (long long)(lh ? a3 : a2) * (D*D)))[hrow];      \
} while (0)

// One step = 2 conns (CC + lh). x fp16 at xh[c*D + 8h..]: ONE b128 read
// (2 broadcast addrs per 16-lane group), 4 fdot2, xor-1 reduce, then even
// lanes stage y[c][row] into fp16 LDS (2-way bank aliasing = free).
#define STEP(CC, WV) do {                                                      \
    int c  = (CC) + lh;                                                        \
    float4 xv = *(const float4*)(xh + (size_t)c * D + (h << 3));               \
    const h2v* xp2 = (const h2v*)&xv;                                          \
    const h2v* wp2 = (const h2v*)&(WV);                                        \
    float p = __builtin_amdgcn_fdot2(wp2[0], xp2[0], 0.0f, false);             \
    p = __builtin_amdgcn_fdot2(wp2[1], xp2[1], p, false);                      \
    p = __builtin_amdgcn_fdot2(wp2[2], xp2[2], p, false);                      \
    p = __builtin_amdgcn_fdot2(wp2[3], xp2[3], p, false);                      \
    p += __shfl_xor(p, 1);  /* y[row] for conn c, row=(lane&31)>>1 */          \
    if (h == 0) yh[c * D + rr] = (_Float16)p;                                  \
} while (0)

#define COMP4(K, W0, W1) do { STEP(4*(K)+0, W0); STEP(4*(K)+2, W1); } while (0)

// load iidx+widx of batch BI into lane-distributed regs (2 VMEM instrs)
#define IDXLOAD(BI, IV, WV) do {                                               \
    int kl = (BI) * 64 + lane; if (kl >= E) kl = E - 1;                        \
    IV = iidx[kl];                                                             \
    WV = widx[kl];                                                             \
} while (0)

// issue the 4 x-gather instrs for the batch whose idx vector is IV
#define XLOAD(IV) do {                                                         \
    int iiu;                                                                   \
    iiu = __shfl(IV,      g4); xq0 = ((const float4*)(values + (long long)iiu * D))[q]; \
    iiu = __shfl(IV, 16 + g4); xq1 = ((const float4*)(values + (long long)iiu * D))[q]; \
    iiu = __shfl(IV, 32 + g4); xq2 = ((const float4*)(values + (long long)iiu * D))[q]; \
    iiu = __shfl(IV, 48 + g4); xq3 = ((const float4*)(values + (long long)iiu * D))[q]; \
} while (0)

// commit one fp32 quarter as fp16 (RN): 8B b64 write at conn*32 + q*8
#define COMMIT(U, XQ) do {                                                     \
    __half2 c0 = __floats2half2_rn((XQ).x, (XQ).y);                            \
    __half2 c1 = __floats2half2_rn((XQ).z, (XQ).w);                            \
    float2 pk;                                                                 \
    ((__half2*)&pk)[0] = c0;                                                   \
    ((__half2*)&pk)[1] = c1;                                                   \
    *(float2*)(xh + ((U)*16 + g4) * D + (q << 2)) = pk;                        \
} while (0)

__global__ __launch_bounds__(TPB, 4) void direct_mv(
    const float* __restrict__ values, const __half* __restrict__ wh,
    const int* __restrict__ iidx, const int* __restrict__ widx,
    float* __restrict__ out, int E)
{
    __shared__ _Float16 xh_all[WPB * 64 * D];   // 2KB/wave: fp16 x
    __shared__ _Float16 yh_all[WPB * 64 * D];   // 2KB/wave: fp16 y staging
    const int lane = threadIdx.x & 63;
    const int wid  = threadIdx.x >> 6;
    _Float16* xh = xh_all + wid * (64 * D);
    _Float16* yh = yh_all + wid * (64 * D);
    const int g4 = lane >> 2;        // gather: conn-in-16
    const int q  = lane & 3;         // gather: quarter
    const int lh   = lane >> 5;      // compute: conn-in-pair (0/1)
    const int h    = lane & 1;       // compute: row half (cols 8h..8h+7)
    const int hrow = lane & 31;      // compute: float4 index into 512B matrix
    const int rr   = (lane & 31) >> 1;  // compute: output row

    const int nbatch = (E + 63) >> 6;
    const int gw = blockIdx.x * WPB + wid;   // global wave id
    const int GW = gridDim.x * WPB;          // total waves
    if (gw >= nbatch) return;

    // ---- prologue: idx 2-deep, x 1-deep ----
    int ivC, wvC, ivN, wvN;
    float4 xq0, xq1, xq2, xq3;
    IDXLOAD(gw, ivC, wvC);           // batch gw idx
    XLOAD(ivC);                      // batch gw x
    if (gw + GW < nbatch) IDXLOAD(gw + GW, ivN, wvN);
    else { ivN = ivC; wvN = wvC; }

    for (int bi = gw; bi < nbatch; bi += GW) {
        // commit current batch x to LDS as fp16 (conn-major, 32B/conn)
        COMMIT(0, xq0);
        COMMIT(1, xq1);
        COMMIT(2, xq2);
        COMMIT(3, xq3);
        int wcur = wvC;
        int k0 = bi * 64;
        int nb = E - k0; if (nb > 64) nb = 64;
        float* outb = out + (long long)k0 * D;

        // pipeline: x of n+1 issues NOW (idx already resident); idx of n+2
        int bn = bi + GW;
        if (bn < nbatch) XLOAD(ivN);
        int bn2 = bi + 2 * GW;
        if (bn2 < nbatch) IDXLOAD(bn2, ivC, wvC);

        // compute: 16 groups of 4 conns; W pipeline DEPTH 4 (8KB in flight)
        float4 A0,A1, B0,B1, C0,C1, E0,E1;
        WPAIR( 0, A0, A1);
        WPAIR( 1, B0, B1);
        WPAIR( 2, C0, C1);
        WPAIR( 3, E0, E1);
        COMP4( 0, A0, A1); WPAIR( 4, A0, A1);
        COMP4( 1, B0, B1); WPAIR( 5, B0, B1);
        COMP4( 2, C0, C1); WPAIR( 6, C0, C1);
        COMP4( 3, E0, E1); WPAIR( 7, E0, E1);
        COMP4( 4, A0, A1); WPAIR( 8, A0, A1);
        COMP4( 5, B0, B1); WPAIR( 9, B0, B1);
        COMP4( 6, C0, C1); WPAIR(10, C0, C1);
        COMP4( 7, E0, E1); WPAIR(11, E0, E1);
        COMP4( 8, A0, A1); WPAIR(12, A0, A1);
        COMP4( 9, B0, B1); WPAIR(13, B0, B1);
        COMP4(10, C0, C1); WPAIR(14, C0, C1);
        COMP4(11, E0, E1); WPAIR(15, E0, E1);
        COMP4(12, A0, A1);
        COMP4(13, B0, B1);
        COMP4(14, C0, C1);
        COMP4(15, E0, E1);

        // drain y staging: 4 dense dwordx4 stores (4KB tile)
        #pragma unroll
        for (int j = 0; j < 4; ++j) {
            float2 raw = *(const float2*)((const char*)yh + j * 512 + lane * 8);
            float2 f0 = __half22float2(((const __half2*)&raw)[0]);
            float2 f1 = __half22float2(((const __half2*)&raw)[1]);
            float4 o;
            o.x = f0.x; o.y = f0.y; o.z = f1.x; o.w = f1.y;
            int cc = j * 16 + (lane >> 2);
            if (cc < nb)
                *(float4*)(outb + (size_t)j * 256 + lane * 4) = o;
        }

        // rotate idx pipeline: N -> current, C(freshly loaded n+2) -> next
        int t;
        t = ivC; ivC = ivN; ivN = t;
        t = wvC; wvC = wvN; wvN = t;
    }
}

extern "C" void kernel_launch(void* const* d_in, const int* in_sizes, int n_in,
                              void* d_out, int out_size, void* d_ws, size_t ws_size,
                              hipStream_t stream) {
    const float* values     = (const float*)d_in[0];
    const float* weight     = (const float*)d_in[1];
    const int*   input_idx  = (const int*)d_in[2];
    const int*   weight_idx = (const int*)d_in[3];
    float*       out        = (float*)d_out;

    int E = in_sizes[2];
    if (E <= 0) return;
    int NW = in_sizes[1] / (D * D);
    size_t need = (size_t)NW * D * D * sizeof(__half);

    if (ws_size < need) {
        int total_thr = E * 4;
        int grid = (total_thr + 255) / 256;
        hipLaunchKernelGGL(linear_gather_mv, dim3(grid), dim3(256), 0, stream,
                           values, weight, input_idx, weight_idx, out, E);
        return;
    }

    __half* wh = (__half*)d_ws;
    int nconv = NW * D * D;
    int cblk = (nconv / 4 + 255) / 256;
    hipLaunchKernelGGL(wconv, dim3(cblk), dim3(256), 0, stream,
                       weight, wh, nconv);

    int nbatch = (E + 63) >> 6;
    int nblk = (nbatch + WPB - 1) / WPB;
    if (nblk > MAXBLK) nblk = MAXBLK;
    hipLaunchKernelGGL(direct_mv, dim3(nblk), dim3(TPB), 0, stream,
                       values, wh, input_idx, weight_idx, out, E);
}